// Round 6
// baseline (291.517 us; speedup 1.0000x reference)
//
#include <hip/hip_runtime.h>
#include <stdint.h>
#include <stddef.h>

// ---------------------------------------------------------------------------
// SelfAttention: out = softmax((x W1^T + b1)(x W2^T + b2)^T) (x W2^T + b2)
// B=4, L=2048, D=1024. fp32 in/out; fp16 MFMA internals.
// Round 6: the r2-r5 sweep proved the single-buffered 2-barrier K-loop is
// latency-bound (all pipes <30% at every tiling/occupancy). This round:
// DOUBLE-BUFFERED LDS K-loop — DMA(k+1) issued before compute(k), one
// __syncthreads()/iter whose vmcnt drain waits on the *prefetch* (hidden by
// compute) instead of the current tile. XOR swizzle kept (r3: conflicts->0).
// ---------------------------------------------------------------------------

typedef _Float16  f16_t;
typedef _Float16  f16x8 __attribute__((ext_vector_type(8)));
typedef float     f32x4 __attribute__((ext_vector_type(4)));

__device__ __forceinline__ f32x4 mfma16(f16x8 a, f16x8 b, f32x4 c) {
  return __builtin_amdgcn_mfma_f32_16x16x32_f16(a, b, c, 0, 0, 0);
}

__device__ __forceinline__ void async_copy16(const f16_t* g, f16_t* l) {
  __builtin_amdgcn_global_load_lds(
      (const __attribute__((address_space(1))) unsigned int*)(g),
      (__attribute__((address_space(3))) unsigned int*)(l),
      16, 0, 0);
}

// C = A * B^T on a (RM*32) x (RN*32) tile, K = nk*32 contiguous in both.
// 4 waves 2x2; wave quadrant (RM*16) x (RN*16). LDS [row][32], 16B k-chunks
// XOR-swizzled by (row>>1)&3. DOUBLE-BUFFERED: As/Bs are 2x tile size.
template <int RM, int RN>
__device__ __forceinline__ void gemm_core_db(
    const f16_t* __restrict__ A, const f16_t* __restrict__ B,
    int lda, int ldb, int nk,
    f16_t* __restrict__ As, f16_t* __restrict__ Bs, f32x4 (&acc)[RM][RN])
{
  constexpr int ASZ = RM * 1024;   // elems per A buffer
  constexpr int BSZ = RN * 1024;
  const int tid  = threadIdx.x;
  const int lane = tid & 63;
  const int w    = tid >> 6;
  const int wr   = (w >> 1) * (RM * 16);
  const int wc   = (w & 1) * (RN * 16);
  const int l16  = lane & 15;
  const int quad = lane >> 4;
  const int sw   = (quad ^ ((l16 >> 1) & 3)) * 8;

  const int r0  = tid >> 2;
  const int kc0 = ((tid & 3) ^ ((r0 >> 1) & 3)) * 8;

  const f16_t* Ag = A + (size_t)r0 * lda + kc0;
  const f16_t* Bg = B + (size_t)r0 * ldb + kc0;

  // prologue: stage tile 0 into buffer 0
#pragma unroll
  for (int h = 0; h < RM / 2; ++h)
    async_copy16(Ag + (size_t)(64 * h) * lda, As + (tid + 256 * h) * 8);
#pragma unroll
  for (int h = 0; h < RN / 2; ++h)
    async_copy16(Bg + (size_t)(64 * h) * ldb, Bs + (tid + 256 * h) * 8);
  __syncthreads();

  for (int kt = 0; kt < nk; ++kt) {
    const int cur = kt & 1;
    const int nxt = cur ^ 1;
    if (kt + 1 < nk) {       // prefetch tile kt+1 into the other buffer
      const f16_t* An = Ag + 32 * (kt + 1);
      const f16_t* Bn = Bg + 32 * (kt + 1);
#pragma unroll
      for (int h = 0; h < RM / 2; ++h)
        async_copy16(An + (size_t)(64 * h) * lda,
                     As + nxt * ASZ + (tid + 256 * h) * 8);
#pragma unroll
      for (int h = 0; h < RN / 2; ++h)
        async_copy16(Bn + (size_t)(64 * h) * ldb,
                     Bs + nxt * BSZ + (tid + 256 * h) * 8);
    }

    const f16_t* Ac = As + cur * ASZ;
    const f16_t* Bc = Bs + cur * BSZ;
    f16x8 af[RM], bf[RN];
#pragma unroll
    for (int i = 0; i < RM; ++i)
      af[i] = *(const f16x8*)(Ac + (wr + i * 16 + l16) * 32 + sw);
#pragma unroll
    for (int j = 0; j < RN; ++j)
      bf[j] = *(const f16x8*)(Bc + (wc + j * 16 + l16) * 32 + sw);
#pragma unroll
    for (int i = 0; i < RM; ++i)
#pragma unroll
      for (int j = 0; j < RN; ++j)
        acc[i][j] = mfma16(af[i], bf[j], acc[i][j]);

    // single barrier: drains my prefetch (hidden by compute) + closes reads
    __syncthreads();
  }
}

// ---------------------------------------------------------------------------
// 0) fp32 -> fp16 converter, 8 elems/thread.
__global__ __launch_bounds__(256) void cvt_kernel(
    const float* __restrict__ in, f16_t* __restrict__ out)
{
  const size_t i = ((size_t)blockIdx.x * 256 + threadIdx.x) * 8;
  f32x4 a = *(const f32x4*)(in + i);
  f32x4 b = *(const f32x4*)(in + i + 4);
  f16x8 o;
#pragma unroll
  for (int k = 0; k < 4; ++k) { o[k] = (f16_t)a[k]; o[k + 4] = (f16_t)b[k]; }
  *(f16x8*)(out + i) = o;
}

// ---------------------------------------------------------------------------
// 1) fused projection, 64x64 tiles, double-buffered: Q = xW1^T+b1,
//    V = xW2^T+b2 (fp16). x tile staged once/iter for both GEMMs.
__global__ __launch_bounds__(256) void proj_qv_kernel(
    const f16_t* __restrict__ X, const f16_t* __restrict__ W1,
    const f16_t* __restrict__ W2, const float* __restrict__ b1,
    const float* __restrict__ b2, f16_t* __restrict__ Q,
    f16_t* __restrict__ V)
{
  __shared__ __align__(16) f16_t Xs[2 * 64 * 32];    // 8 KB
  __shared__ __align__(16) f16_t W1s[2 * 64 * 32];   // 8 KB
  __shared__ __align__(16) f16_t W2s[2 * 64 * 32];   // 8 KB
  constexpr int SZ = 64 * 32;

  const int m0 = blockIdx.x * 64;
  const int n0 = blockIdx.y * 64;

  const int tid  = threadIdx.x;
  const int lane = tid & 63;
  const int w    = tid >> 6;
  const int wr   = (w >> 1) * 32;
  const int wc   = (w & 1) * 32;
  const int quad = lane >> 4;
  const int l16  = lane & 15;
  const int sw   = (quad ^ ((l16 >> 1) & 3)) * 8;
  const int r0   = tid >> 2;
  const int kc0  = ((tid & 3) ^ ((r0 >> 1) & 3)) * 8;

  const f16_t* Xg = X + (size_t)(m0 + r0) * 1024 + kc0;
  const f16_t* G1 = W1 + (size_t)(n0 + r0) * 1024 + kc0;
  const f16_t* G2 = W2 + (size_t)(n0 + r0) * 1024 + kc0;

  f32x4 accQ[2][2] = {};
  f32x4 accV[2][2] = {};

  // prologue -> buffer 0
  async_copy16(Xg, Xs + tid * 8);
  async_copy16(G1, W1s + tid * 8);
  async_copy16(G2, W2s + tid * 8);
  __syncthreads();

  for (int kt = 0; kt < 32; ++kt) {
    const int cur = kt & 1;
    const int nxt = cur ^ 1;
    if (kt + 1 < 32) {
      const int o = 32 * (kt + 1);
      async_copy16(Xg + o, Xs + nxt * SZ + tid * 8);
      async_copy16(G1 + o, W1s + nxt * SZ + tid * 8);
      async_copy16(G2 + o, W2s + nxt * SZ + tid * 8);
    }

    f16x8 xf[2], w1f[2], w2f[2];
#pragma unroll
    for (int i = 0; i < 2; ++i) {
      xf[i]  = *(const f16x8*)(Xs  + cur * SZ + (wr + i * 16 + l16) * 32 + sw);
      w1f[i] = *(const f16x8*)(W1s + cur * SZ + (wc + i * 16 + l16) * 32 + sw);
      w2f[i] = *(const f16x8*)(W2s + cur * SZ + (wc + i * 16 + l16) * 32 + sw);
    }
#pragma unroll
    for (int i = 0; i < 2; ++i)
#pragma unroll
      for (int j = 0; j < 2; ++j) {
        accQ[i][j] = mfma16(xf[i], w1f[j], accQ[i][j]);
        accV[i][j] = mfma16(xf[i], w2f[j], accV[i][j]);
      }
    __syncthreads();
  }

#pragma unroll
  for (int j = 0; j < 2; ++j) {
    const int col = n0 + wc + j * 16 + l16;
    const float bq = b1[col], bv = b2[col];
#pragma unroll
    for (int i = 0; i < 2; ++i)
#pragma unroll
      for (int r = 0; r < 4; ++r) {
        const int row = m0 + wr + i * 16 + quad * 4 + r;
        Q[(size_t)row * 1024 + col] = (f16_t)(accQ[i][j][r] + bq);
        V[(size_t)row * 1024 + col] = (f16_t)(accV[i][j][r] + bv);
      }
  }
}

// ---------------------------------------------------------------------------
// 1b) Vt[b][d][key] = V[b][key][d]. 64x64 tiles through LDS, XOR-swizzled,
//     conflict-free, coalesced both sides. Grid (32 key, 16 d, 4 b).
__global__ __launch_bounds__(256) void vt_kernel(
    const f16_t* __restrict__ V, f16_t* __restrict__ Vt)
{
  __shared__ __align__(16) f16_t Ls[64 * 64];   // 8 KB
  const int key0 = blockIdx.x * 64;
  const int d0   = blockIdx.y * 64;
  const size_t boff = (size_t)blockIdx.z * 2048 * 1024;

  const int tid = threadIdx.x;
#pragma unroll
  for (int rep = 0; rep < 2; ++rep) {
    const int kr = rep * 32 + (tid >> 3);
    const int dc = (tid & 7) * 8;
    f16x8 v = *(const f16x8*)(V + boff + (size_t)(key0 + kr) * 1024 + d0 + dc);
#pragma unroll
    for (int e = 0; e < 8; ++e) {
      const int d = dc + e;
      Ls[d * 64 + (((kr >> 3) ^ (d >> 3)) << 3) + (kr & 7)] = v[e];
    }
  }
  __syncthreads();
#pragma unroll
  for (int rep = 0; rep < 2; ++rep) {
    const int d = rep * 32 + (tid >> 3);
    const int c = tid & 7;
    f16x8 v = *(const f16x8*)(Ls + d * 64 + ((c ^ (d >> 3)) << 3));
    *(f16x8*)(Vt + boff + (size_t)(d0 + d) * 2048 + key0 + c * 8) = v;
  }
}

// ---------------------------------------------------------------------------
// 2) scores: S[b][q][k] = Q[b,q,:] . V[b,k,:] (fp32). 128x128 tile (best
//    measured), double-buffered (LDS 32 KB). Grid 16x16x4 = 1024.
__global__ __launch_bounds__(256) void score_kernel(
    const f16_t* __restrict__ Q, const f16_t* __restrict__ V,
    float* __restrict__ S)
{
  __shared__ __align__(16) f16_t As[2 * 128 * 32];   // 16 KB
  __shared__ __align__(16) f16_t Bs[2 * 128 * 32];   // 16 KB
  const int m0 = blockIdx.x * 128;
  const int n0 = blockIdx.y * 128;
  const size_t boff = (size_t)blockIdx.z * 2048 * 1024;

  f32x4 acc[4][4] = {};
  gemm_core_db<4, 4>(Q + boff + (size_t)m0 * 1024,
                     V + boff + (size_t)n0 * 1024,
                     1024, 1024, 1024 / 32, As, Bs, acc);

  float* Sb = S + (size_t)blockIdx.z * 2048 * 2048;
  const int lane = threadIdx.x & 63;
  const int w    = threadIdx.x >> 6;
  const int wr   = (w >> 1) * 64, wc = (w & 1) * 64;
  const int quad = lane >> 4,     l16 = lane & 15;

#pragma unroll
  for (int i = 0; i < 4; ++i)
#pragma unroll
    for (int j = 0; j < 4; ++j)
#pragma unroll
      for (int r = 0; r < 4; ++r) {
        const int row = m0 + wr + i * 16 + quad * 4 + r;
        const int col = n0 + wc + j * 16 + l16;
        Sb[(size_t)row * 2048 + col] = acc[i][j][r];
      }
}

// ---------------------------------------------------------------------------
// 3) softmax over each 2048-fp32 row of S; fp16 P written in-place.
__global__ __launch_bounds__(256) void softmax_kernel(float* __restrict__ S)
{
  float* src = S + (size_t)blockIdx.x * 2048;
  f16_t* dst = (f16_t*)src;
  const int tid  = threadIdx.x;
  const int lane = tid & 63;
  const int w    = tid >> 6;

  f32x4 va = *((const f32x4*)src + tid * 2);
  f32x4 vb = *((const f32x4*)src + tid * 2 + 1);
  float f[8];
#pragma unroll
  for (int k = 0; k < 4; ++k) { f[k] = va[k]; f[k + 4] = vb[k]; }

  float m = f[0];
#pragma unroll
  for (int k = 1; k < 8; ++k) m = fmaxf(m, f[k]);
#pragma unroll
  for (int off = 32; off >= 1; off >>= 1) m = fmaxf(m, __shfl_xor(m, off));

  __shared__ float red[4];
  if (lane == 0) red[w] = m;
  __syncthreads();
  m = fmaxf(fmaxf(red[0], red[1]), fmaxf(red[2], red[3]));

  float s = 0.f;
#pragma unroll
  for (int k = 0; k < 8; ++k) { f[k] = __expf(f[k] - m); s += f[k]; }
#pragma unroll
  for (int off = 32; off >= 1; off >>= 1) s += __shfl_xor(s, off);
  __syncthreads();
  if (lane == 0) red[w] = s;
  __syncthreads();
  s = (red[0] + red[1]) + (red[2] + red[3]);
  const float inv = 1.f / s;

  f16x8 o;
#pragma unroll
  for (int k = 0; k < 8; ++k) o[k] = (f16_t)(f[k] * inv);
  *((f16x8*)dst + tid) = o;
}

// ---------------------------------------------------------------------------
// 4) out[b][q][d] = sum_k P[b][q][k] * Vt[b][d][k] -> fp32. P pitch 4096 f16.
//    64x128 tile, double-buffered (LDS 24 KB). Grid 32x8x4 = 1024.
__global__ __launch_bounds__(256) void out_kernel(
    const f16_t* __restrict__ P, const f16_t* __restrict__ Vt,
    float* __restrict__ Out)
{
  __shared__ __align__(16) f16_t As[2 * 64 * 32];    // 8 KB
  __shared__ __align__(16) f16_t Bs[2 * 128 * 32];   // 16 KB
  const int m0 = blockIdx.x * 64;
  const int n0 = blockIdx.y * 128;
  const size_t poff  = (size_t)blockIdx.z * 2048 * 4096;
  const size_t vtoff = (size_t)blockIdx.z * 1024 * 2048;

  f32x4 acc[2][4] = {};
  gemm_core_db<2, 4>(P + poff + (size_t)m0 * 4096,
                     Vt + vtoff + (size_t)n0 * 2048,
                     4096, 2048, 2048 / 32, As, Bs, acc);

  float* Ob = Out + (size_t)blockIdx.z * 2048 * 1024;
  const int lane = threadIdx.x & 63;
  const int w    = threadIdx.x >> 6;
  const int wr   = (w >> 1) * 32, wc = (w & 1) * 64;
  const int quad = lane >> 4,     l16 = lane & 15;

#pragma unroll
  for (int i = 0; i < 2; ++i)
#pragma unroll
    for (int j = 0; j < 4; ++j)
#pragma unroll
      for (int r = 0; r < 4; ++r) {
        const int row = m0 + wr + i * 16 + quad * 4 + r;
        const int col = n0 + wc + j * 16 + l16;
        Ob[(size_t)row * 1024 + col] = acc[i][j][r];
      }
}

// ---------------------------------------------------------------------------
extern "C" void kernel_launch(void* const* d_in, const int* in_sizes, int n_in,
                              void* d_out, int out_size, void* d_ws, size_t ws_size,
                              hipStream_t stream) {
  const float* x  = (const float*)d_in[0];
  const float* W1 = (const float*)d_in[1];
  const float* b1 = (const float*)d_in[2];
  const float* W2 = (const float*)d_in[3];
  const float* b2 = (const float*)d_in[4];
  float* out = (float*)d_out;

  const size_t QN = (size_t)8192 * 1024;
  const size_t WN = (size_t)1024 * 1024;
  f16_t* xh  = (f16_t*)d_ws;       // 16 MiB
  f16_t* W1h = xh + QN;            //  2 MiB
  f16_t* W2h = W1h + WN;           //  2 MiB
  f16_t* Q   = W2h + WN;           // 16 MiB
  f16_t* V   = Q + QN;             // 16 MiB
  f16_t* Vt  = V + QN;             // 16 MiB [4][1024][2048]
  float* S   = (float*)(Vt + QN);  // 64 MiB [4][2048][2048], P fp16 in-place

  dim3 blk(256);
  cvt_kernel<<<4096, blk, 0, stream>>>(x, xh);
  cvt_kernel<<<512, blk, 0, stream>>>(W1, W1h);
  cvt_kernel<<<512, blk, 0, stream>>>(W2, W2h);
  proj_qv_kernel<<<dim3(128, 16), blk, 0, stream>>>(xh, W1h, W2h, b1, b2, Q, V);
  vt_kernel<<<dim3(32, 16, 4), blk, 0, stream>>>(V, Vt);
  score_kernel<<<dim3(16, 16, 4), blk, 0, stream>>>(Q, V, S);
  softmax_kernel<<<8192, blk, 0, stream>>>(S);
  out_kernel<<<dim3(32, 8, 4), blk, 0, stream>>>((const f16_t*)S, Vt, out);
}

// Round 7
// 262.956 us; speedup vs baseline: 1.1086x; 1.1086x over previous
//
#include <hip/hip_runtime.h>
#include <stdint.h>
#include <stddef.h>

// ---------------------------------------------------------------------------
// SelfAttention: out = softmax((x W1^T + b1)(x W2^T + b2)^T) (x W2^T + b2)
// B=4, L=2048, D=1024. fp32 in/out; fp16 MFMA internals.
// Round 7: r2-r6 proved the BK=32 2-barrier K-loop is latency-bound at every
// tiling/occupancy/dbuf setting (all pipes <30%). The un-isolated knob is
// BARRIER FREQUENCY: this round stages TWO 32-k slices per barrier pair
// (BK=64) -> barriers halve, 32 MFMA/wave per interval (AITER-like), same
// fragment working set, same grids/occupancy. XOR swizzle kept (r3 result).
// Also merged the 3 cvt launches into 1.
// ---------------------------------------------------------------------------

typedef _Float16  f16_t;
typedef _Float16  f16x8 __attribute__((ext_vector_type(8)));
typedef float     f32x4 __attribute__((ext_vector_type(4)));

__device__ __forceinline__ f32x4 mfma16(f16x8 a, f16x8 b, f32x4 c) {
  return __builtin_amdgcn_mfma_f32_16x16x32_f16(a, b, c, 0, 0, 0);
}

__device__ __forceinline__ void async_copy16(const f16_t* g, f16_t* l) {
  __builtin_amdgcn_global_load_lds(
      (const __attribute__((address_space(1))) unsigned int*)(g),
      (__attribute__((address_space(3))) unsigned int*)(l),
      16, 0, 0);
}

// C = A * B^T on a (RM*32) x (RN*32) tile, K = nk64*64, K contiguous.
// 4 waves 2x2; wave quadrant (RM*16) x (RN*16). Per iter: stage two 32-k
// slices (halves s=0,1), one barrier pair, 2 x (RM*RN) MFMAs per wave.
// LDS per array: 2 halves x (RM|RN)*1024 elems. k-chunks XOR-swizzled.
template <int RM, int RN>
__device__ __forceinline__ void gemm_core(
    const f16_t* __restrict__ A, const f16_t* __restrict__ B,
    int lda, int ldb, int nk64,
    f16_t* __restrict__ As, f16_t* __restrict__ Bs, f32x4 (&acc)[RM][RN])
{
  const int tid  = threadIdx.x;
  const int lane = tid & 63;
  const int w    = tid >> 6;
  const int wr   = (w >> 1) * (RM * 16);
  const int wc   = (w & 1) * (RN * 16);
  const int l16  = lane & 15;
  const int quad = lane >> 4;
  const int sw   = (quad ^ ((l16 >> 1) & 3)) * 8;

  const int r0  = tid >> 2;
  const int kc0 = ((tid & 3) ^ ((r0 >> 1) & 3)) * 8;

  const f16_t* Ag = A + (size_t)r0 * lda + kc0;
  const f16_t* Bg = B + (size_t)r0 * ldb + kc0;

  for (int kt = 0; kt < nk64; ++kt) {
#pragma unroll
    for (int s = 0; s < 2; ++s) {
      const int ko = s * 32;
#pragma unroll
      for (int h = 0; h < RM / 2; ++h)
        async_copy16(Ag + ko + (size_t)(64 * h) * lda,
                     As + s * RM * 1024 + (tid + 256 * h) * 8);
#pragma unroll
      for (int h = 0; h < RN / 2; ++h)
        async_copy16(Bg + ko + (size_t)(64 * h) * ldb,
                     Bs + s * RN * 1024 + (tid + 256 * h) * 8);
    }
    __syncthreads();

#pragma unroll
    for (int s = 0; s < 2; ++s) {
      const f16_t* Ac = As + s * RM * 1024;
      const f16_t* Bc = Bs + s * RN * 1024;
      f16x8 af[RM], bf[RN];
#pragma unroll
      for (int i = 0; i < RM; ++i)
        af[i] = *(const f16x8*)(Ac + (wr + i * 16 + l16) * 32 + sw);
#pragma unroll
      for (int j = 0; j < RN; ++j)
        bf[j] = *(const f16x8*)(Bc + (wc + j * 16 + l16) * 32 + sw);
#pragma unroll
      for (int i = 0; i < RM; ++i)
#pragma unroll
        for (int j = 0; j < RN; ++j)
          acc[i][j] = mfma16(af[i], bf[j], acc[i][j]);
    }

    __syncthreads();
    Ag += 64; Bg += 64;
  }
}

// ---------------------------------------------------------------------------
// 0) fp32 -> fp16 for x, W1, W2 in one launch. Grid 5120 x 256 x 8 elems.
__global__ __launch_bounds__(256) void cvt_kernel(
    const float* __restrict__ x, const float* __restrict__ W1,
    const float* __restrict__ W2, f16_t* __restrict__ xh,
    f16_t* __restrict__ W1h, f16_t* __restrict__ W2h)
{
  const size_t XN = (size_t)8192 * 1024;
  const size_t WN = (size_t)1024 * 1024;
  size_t i = ((size_t)blockIdx.x * 256 + threadIdx.x) * 8;
  const float* in; f16_t* out;
  if (i < XN)            { in = x;  out = xh; }
  else if (i < XN + WN)  { in = W1; out = W1h; i -= XN; }
  else                   { in = W2; out = W2h; i -= XN + WN; }
  f32x4 a = *(const f32x4*)(in + i);
  f32x4 b = *(const f32x4*)(in + i + 4);
  f16x8 o;
#pragma unroll
  for (int k = 0; k < 4; ++k) { o[k] = (f16_t)a[k]; o[k + 4] = (f16_t)b[k]; }
  *(f16x8*)(out + i) = o;
}

// ---------------------------------------------------------------------------
// 1) fused projection, 64x64 tiles, BK=64: Q = xW1^T+b1, V = xW2^T+b2.
//    x slices staged once per iter for both GEMMs. Grid 128x16=2048.
__global__ __launch_bounds__(256) void proj_qv_kernel(
    const f16_t* __restrict__ X, const f16_t* __restrict__ W1,
    const f16_t* __restrict__ W2, const float* __restrict__ b1,
    const float* __restrict__ b2, f16_t* __restrict__ Q,
    f16_t* __restrict__ V)
{
  __shared__ __align__(16) f16_t Xs[2 * 64 * 32];    // 8 KB
  __shared__ __align__(16) f16_t W1s[2 * 64 * 32];   // 8 KB
  __shared__ __align__(16) f16_t W2s[2 * 64 * 32];   // 8 KB
  constexpr int SZ = 64 * 32;

  const int m0 = blockIdx.x * 64;
  const int n0 = blockIdx.y * 64;

  const int tid  = threadIdx.x;
  const int lane = tid & 63;
  const int w    = tid >> 6;
  const int wr   = (w >> 1) * 32;
  const int wc   = (w & 1) * 32;
  const int quad = lane >> 4;
  const int l16  = lane & 15;
  const int sw   = (quad ^ ((l16 >> 1) & 3)) * 8;
  const int r0   = tid >> 2;
  const int kc0  = ((tid & 3) ^ ((r0 >> 1) & 3)) * 8;

  const f16_t* Xg = X + (size_t)(m0 + r0) * 1024 + kc0;
  const f16_t* G1 = W1 + (size_t)(n0 + r0) * 1024 + kc0;
  const f16_t* G2 = W2 + (size_t)(n0 + r0) * 1024 + kc0;

  f32x4 accQ[2][2] = {};
  f32x4 accV[2][2] = {};

  for (int kt = 0; kt < 16; ++kt) {
#pragma unroll
    for (int s = 0; s < 2; ++s) {
      const int ko = s * 32;
      async_copy16(Xg + ko, Xs + s * SZ + tid * 8);
      async_copy16(G1 + ko, W1s + s * SZ + tid * 8);
      async_copy16(G2 + ko, W2s + s * SZ + tid * 8);
    }
    __syncthreads();

#pragma unroll
    for (int s = 0; s < 2; ++s) {
      f16x8 xf[2], w1f[2], w2f[2];
#pragma unroll
      for (int i = 0; i < 2; ++i) {
        xf[i]  = *(const f16x8*)(Xs  + s * SZ + (wr + i * 16 + l16) * 32 + sw);
        w1f[i] = *(const f16x8*)(W1s + s * SZ + (wc + i * 16 + l16) * 32 + sw);
        w2f[i] = *(const f16x8*)(W2s + s * SZ + (wc + i * 16 + l16) * 32 + sw);
      }
#pragma unroll
      for (int i = 0; i < 2; ++i)
#pragma unroll
        for (int j = 0; j < 2; ++j) {
          accQ[i][j] = mfma16(xf[i], w1f[j], accQ[i][j]);
          accV[i][j] = mfma16(xf[i], w2f[j], accV[i][j]);
        }
    }
    __syncthreads();
    Xg += 64; G1 += 64; G2 += 64;
  }

#pragma unroll
  for (int j = 0; j < 2; ++j) {
    const int col = n0 + wc + j * 16 + l16;
    const float bq = b1[col], bv = b2[col];
#pragma unroll
    for (int i = 0; i < 2; ++i)
#pragma unroll
      for (int r = 0; r < 4; ++r) {
        const int row = m0 + wr + i * 16 + quad * 4 + r;
        Q[(size_t)row * 1024 + col] = (f16_t)(accQ[i][j][r] + bq);
        V[(size_t)row * 1024 + col] = (f16_t)(accV[i][j][r] + bv);
      }
  }
}

// ---------------------------------------------------------------------------
// 1b) Vt[b][d][key] = V[b][key][d]. 64x64 tiles through LDS, XOR-swizzled,
//     conflict-free, coalesced both sides. Grid (32 key, 16 d, 4 b).
__global__ __launch_bounds__(256) void vt_kernel(
    const f16_t* __restrict__ V, f16_t* __restrict__ Vt)
{
  __shared__ __align__(16) f16_t Ls[64 * 64];   // 8 KB
  const int key0 = blockIdx.x * 64;
  const int d0   = blockIdx.y * 64;
  const size_t boff = (size_t)blockIdx.z * 2048 * 1024;

  const int tid = threadIdx.x;
#pragma unroll
  for (int rep = 0; rep < 2; ++rep) {
    const int kr = rep * 32 + (tid >> 3);
    const int dc = (tid & 7) * 8;
    f16x8 v = *(const f16x8*)(V + boff + (size_t)(key0 + kr) * 1024 + d0 + dc);
#pragma unroll
    for (int e = 0; e < 8; ++e) {
      const int d = dc + e;
      Ls[d * 64 + (((kr >> 3) ^ (d >> 3)) << 3) + (kr & 7)] = v[e];
    }
  }
  __syncthreads();
#pragma unroll
  for (int rep = 0; rep < 2; ++rep) {
    const int d = rep * 32 + (tid >> 3);
    const int c = tid & 7;
    f16x8 v = *(const f16x8*)(Ls + d * 64 + ((c ^ (d >> 3)) << 3));
    *(f16x8*)(Vt + boff + (size_t)(d0 + d) * 2048 + key0 + c * 8) = v;
  }
}

// ---------------------------------------------------------------------------
// 2) scores: S[b][q][k] = Q[b,q,:] . V[b,k,:] (fp32). 128x128 tile, BK=64,
//    LDS 32 KB, grid 16x16x4 = 1024 (4 blocks/CU), 16 barrier pairs.
__global__ __launch_bounds__(256) void score_kernel(
    const f16_t* __restrict__ Q, const f16_t* __restrict__ V,
    float* __restrict__ S)
{
  __shared__ __align__(16) f16_t As[2 * 128 * 32];   // 16 KB
  __shared__ __align__(16) f16_t Bs[2 * 128 * 32];   // 16 KB
  const int m0 = blockIdx.x * 128;
  const int n0 = blockIdx.y * 128;
  const size_t boff = (size_t)blockIdx.z * 2048 * 1024;

  f32x4 acc[4][4] = {};
  gemm_core<4, 4>(Q + boff + (size_t)m0 * 1024,
                  V + boff + (size_t)n0 * 1024,
                  1024, 1024, 1024 / 64, As, Bs, acc);

  float* Sb = S + (size_t)blockIdx.z * 2048 * 2048;
  const int lane = threadIdx.x & 63;
  const int w    = threadIdx.x >> 6;
  const int wr   = (w >> 1) * 64, wc = (w & 1) * 64;
  const int quad = lane >> 4,     l16 = lane & 15;

#pragma unroll
  for (int i = 0; i < 4; ++i)
#pragma unroll
    for (int j = 0; j < 4; ++j)
#pragma unroll
      for (int r = 0; r < 4; ++r) {
        const int row = m0 + wr + i * 16 + quad * 4 + r;
        const int col = n0 + wc + j * 16 + l16;
        Sb[(size_t)row * 2048 + col] = acc[i][j][r];
      }
}

// ---------------------------------------------------------------------------
// 3) softmax over each 2048-fp32 row of S; fp16 P written in-place.
__global__ __launch_bounds__(256) void softmax_kernel(float* __restrict__ S)
{
  float* src = S + (size_t)blockIdx.x * 2048;
  f16_t* dst = (f16_t*)src;
  const int tid  = threadIdx.x;
  const int lane = tid & 63;
  const int w    = tid >> 6;

  f32x4 va = *((const f32x4*)src + tid * 2);
  f32x4 vb = *((const f32x4*)src + tid * 2 + 1);
  float f[8];
#pragma unroll
  for (int k = 0; k < 4; ++k) { f[k] = va[k]; f[k + 4] = vb[k]; }

  float m = f[0];
#pragma unroll
  for (int k = 1; k < 8; ++k) m = fmaxf(m, f[k]);
#pragma unroll
  for (int off = 32; off >= 1; off >>= 1) m = fmaxf(m, __shfl_xor(m, off));

  __shared__ float red[4];
  if (lane == 0) red[w] = m;
  __syncthreads();
  m = fmaxf(fmaxf(red[0], red[1]), fmaxf(red[2], red[3]));

  float s = 0.f;
#pragma unroll
  for (int k = 0; k < 8; ++k) { f[k] = __expf(f[k] - m); s += f[k]; }
#pragma unroll
  for (int off = 32; off >= 1; off >>= 1) s += __shfl_xor(s, off);
  __syncthreads();
  if (lane == 0) red[w] = s;
  __syncthreads();
  s = (red[0] + red[1]) + (red[2] + red[3]);
  const float inv = 1.f / s;

  f16x8 o;
#pragma unroll
  for (int k = 0; k < 8; ++k) o[k] = (f16_t)(f[k] * inv);
  *((f16x8*)dst + tid) = o;
}

// ---------------------------------------------------------------------------
// 4) out[b][q][d] = sum_k P[b][q][k] * Vt[b][d][k] -> fp32. P pitch 4096 f16.
//    64x128 tile, BK=64 (LDS 24 KB), grid 32x8x4 = 1024, 32 barrier pairs.
__global__ __launch_bounds__(256) void out_kernel(
    const f16_t* __restrict__ P, const f16_t* __restrict__ Vt,
    float* __restrict__ Out)
{
  __shared__ __align__(16) f16_t As[2 * 64 * 32];    // 8 KB
  __shared__ __align__(16) f16_t Bs[2 * 128 * 32];   // 16 KB
  const int m0 = blockIdx.x * 64;
  const int n0 = blockIdx.y * 128;
  const size_t poff  = (size_t)blockIdx.z * 2048 * 4096;
  const size_t vtoff = (size_t)blockIdx.z * 1024 * 2048;

  f32x4 acc[2][4] = {};
  gemm_core<2, 4>(P + poff + (size_t)m0 * 4096,
                  Vt + vtoff + (size_t)n0 * 2048,
                  4096, 2048, 2048 / 64, As, Bs, acc);

  float* Ob = Out + (size_t)blockIdx.z * 2048 * 1024;
  const int lane = threadIdx.x & 63;
  const int w    = threadIdx.x >> 6;
  const int wr   = (w >> 1) * 32, wc = (w & 1) * 64;
  const int quad = lane >> 4,     l16 = lane & 15;

#pragma unroll
  for (int i = 0; i < 2; ++i)
#pragma unroll
    for (int j = 0; j < 4; ++j)
#pragma unroll
      for (int r = 0; r < 4; ++r) {
        const int row = m0 + wr + i * 16 + quad * 4 + r;
        const int col = n0 + wc + j * 16 + l16;
        Ob[(size_t)row * 1024 + col] = acc[i][j][r];
      }
}

// ---------------------------------------------------------------------------
extern "C" void kernel_launch(void* const* d_in, const int* in_sizes, int n_in,
                              void* d_out, int out_size, void* d_ws, size_t ws_size,
                              hipStream_t stream) {
  const float* x  = (const float*)d_in[0];
  const float* W1 = (const float*)d_in[1];
  const float* b1 = (const float*)d_in[2];
  const float* W2 = (const float*)d_in[3];
  const float* b2 = (const float*)d_in[4];
  float* out = (float*)d_out;

  const size_t QN = (size_t)8192 * 1024;
  const size_t WN = (size_t)1024 * 1024;
  f16_t* xh  = (f16_t*)d_ws;       // 16 MiB
  f16_t* W1h = xh + QN;            //  2 MiB
  f16_t* W2h = W1h + WN;           //  2 MiB
  f16_t* Q   = W2h + WN;           // 16 MiB
  f16_t* V   = Q + QN;             // 16 MiB
  f16_t* Vt  = V + QN;             // 16 MiB [4][1024][2048]
  float* S   = (float*)(Vt + QN);  // 64 MiB [4][2048][2048], P fp16 in-place

  dim3 blk(256);
  cvt_kernel<<<5120, blk, 0, stream>>>(x, W1, W2, xh, W1h, W2h);
  proj_qv_kernel<<<dim3(128, 16), blk, 0, stream>>>(xh, W1h, W2h, b1, b2, Q, V);
  vt_kernel<<<dim3(32, 16, 4), blk, 0, stream>>>(V, Vt);
  score_kernel<<<dim3(16, 16, 4), blk, 0, stream>>>(Q, V, S);
  softmax_kernel<<<8192, blk, 0, stream>>>(S);
  out_kernel<<<dim3(32, 8, 4), blk, 0, stream>>>((const f16_t*)S, Vt, out);
}

// Round 8
// 258.551 us; speedup vs baseline: 1.1275x; 1.0170x over previous
//
#include <hip/hip_runtime.h>
#include <stdint.h>
#include <stddef.h>

// ---------------------------------------------------------------------------
// SelfAttention: out = softmax((x W1^T + b1)(x W2^T + b2)^T) (x W2^T + b2)
// B=4, L=2048, D=1024. fp32 in/out; fp16 MFMA internals.
// Round 8: r7 confirmed barrier frequency is the lever (BK=32->64: out 74->57,
// total 291->263). This round pushes the same gradient:
//  - out: BK=128 (4 slices/barrier-pair, LDS 48 KB, 3 blocks/CU, 16 barriers)
//  - S stored fp16 (score writes 32 MiB not 64; softmax traffic 96->64 MiB;
//    exp/sum still fp32 — peaked softmax makes pre-exp quantization ~0.004)
//  - score/proj stay BK=64 (score@BK=128 would be 64 KB LDS = 2 blocks/CU,
//    the m132-measured cliff). XOR swizzle everywhere (r3: conflicts->0).
// ---------------------------------------------------------------------------

typedef _Float16  f16_t;
typedef _Float16  f16x8 __attribute__((ext_vector_type(8)));
typedef float     f32x4 __attribute__((ext_vector_type(4)));

__device__ __forceinline__ f32x4 mfma16(f16x8 a, f16x8 b, f32x4 c) {
  return __builtin_amdgcn_mfma_f32_16x16x32_f16(a, b, c, 0, 0, 0);
}

__device__ __forceinline__ void async_copy16(const f16_t* g, f16_t* l) {
  __builtin_amdgcn_global_load_lds(
      (const __attribute__((address_space(1))) unsigned int*)(g),
      (__attribute__((address_space(3))) unsigned int*)(l),
      16, 0, 0);
}

// C = A * B^T on a (RM*32) x (RN*32) tile, K = nk*NS*32, K contiguous.
// 4 waves 2x2; wave quadrant (RM*16) x (RN*16). Per iter: stage NS 32-k
// slices, one barrier pair, NS*RM*RN MFMAs per wave. k-chunks XOR-swizzled.
template <int RM, int RN, int NS>
__device__ __forceinline__ void gemm_core(
    const f16_t* __restrict__ A, const f16_t* __restrict__ B,
    int lda, int ldb, int nk,
    f16_t* __restrict__ As, f16_t* __restrict__ Bs, f32x4 (&acc)[RM][RN])
{
  const int tid  = threadIdx.x;
  const int lane = tid & 63;
  const int w    = tid >> 6;
  const int wr   = (w >> 1) * (RM * 16);
  const int wc   = (w & 1) * (RN * 16);
  const int l16  = lane & 15;
  const int quad = lane >> 4;
  const int sw   = (quad ^ ((l16 >> 1) & 3)) * 8;

  const int r0  = tid >> 2;
  const int kc0 = ((tid & 3) ^ ((r0 >> 1) & 3)) * 8;

  const f16_t* Ag = A + (size_t)r0 * lda + kc0;
  const f16_t* Bg = B + (size_t)r0 * ldb + kc0;

  for (int kt = 0; kt < nk; ++kt) {
#pragma unroll
    for (int s = 0; s < NS; ++s) {
      const int ko = s * 32;
#pragma unroll
      for (int h = 0; h < RM / 2; ++h)
        async_copy16(Ag + ko + (size_t)(64 * h) * lda,
                     As + s * RM * 1024 + (tid + 256 * h) * 8);
#pragma unroll
      for (int h = 0; h < RN / 2; ++h)
        async_copy16(Bg + ko + (size_t)(64 * h) * ldb,
                     Bs + s * RN * 1024 + (tid + 256 * h) * 8);
    }
    __syncthreads();

#pragma unroll
    for (int s = 0; s < NS; ++s) {
      const f16_t* Ac = As + s * RM * 1024;
      const f16_t* Bc = Bs + s * RN * 1024;
      f16x8 af[RM], bf[RN];
#pragma unroll
      for (int i = 0; i < RM; ++i)
        af[i] = *(const f16x8*)(Ac + (wr + i * 16 + l16) * 32 + sw);
#pragma unroll
      for (int j = 0; j < RN; ++j)
        bf[j] = *(const f16x8*)(Bc + (wc + j * 16 + l16) * 32 + sw);
#pragma unroll
      for (int i = 0; i < RM; ++i)
#pragma unroll
        for (int j = 0; j < RN; ++j)
          acc[i][j] = mfma16(af[i], bf[j], acc[i][j]);
    }

    __syncthreads();
    Ag += NS * 32; Bg += NS * 32;
  }
}

// ---------------------------------------------------------------------------
// 0) fp32 -> fp16 for x, W1, W2 in one launch. Grid 5120 x 256 x 8 elems.
__global__ __launch_bounds__(256) void cvt_kernel(
    const float* __restrict__ x, const float* __restrict__ W1,
    const float* __restrict__ W2, f16_t* __restrict__ xh,
    f16_t* __restrict__ W1h, f16_t* __restrict__ W2h)
{
  const size_t XN = (size_t)8192 * 1024;
  const size_t WN = (size_t)1024 * 1024;
  size_t i = ((size_t)blockIdx.x * 256 + threadIdx.x) * 8;
  const float* in; f16_t* out;
  if (i < XN)            { in = x;  out = xh; }
  else if (i < XN + WN)  { in = W1; out = W1h; i -= XN; }
  else                   { in = W2; out = W2h; i -= XN + WN; }
  f32x4 a = *(const f32x4*)(in + i);
  f32x4 b = *(const f32x4*)(in + i + 4);
  f16x8 o;
#pragma unroll
  for (int k = 0; k < 4; ++k) { o[k] = (f16_t)a[k]; o[k + 4] = (f16_t)b[k]; }
  *(f16x8*)(out + i) = o;
}

// ---------------------------------------------------------------------------
// 1) fused projection, 64x64 tiles, BK=64: Q = xW1^T+b1, V = xW2^T+b2.
//    x slices staged once per iter for both GEMMs. Grid 128x16=2048.
__global__ __launch_bounds__(256) void proj_qv_kernel(
    const f16_t* __restrict__ X, const f16_t* __restrict__ W1,
    const f16_t* __restrict__ W2, const float* __restrict__ b1,
    const float* __restrict__ b2, f16_t* __restrict__ Q,
    f16_t* __restrict__ V)
{
  __shared__ __align__(16) f16_t Xs[2 * 64 * 32];    // 8 KB
  __shared__ __align__(16) f16_t W1s[2 * 64 * 32];   // 8 KB
  __shared__ __align__(16) f16_t W2s[2 * 64 * 32];   // 8 KB
  constexpr int SZ = 64 * 32;

  const int m0 = blockIdx.x * 64;
  const int n0 = blockIdx.y * 64;

  const int tid  = threadIdx.x;
  const int lane = tid & 63;
  const int w    = tid >> 6;
  const int wr   = (w >> 1) * 32;
  const int wc   = (w & 1) * 32;
  const int quad = lane >> 4;
  const int l16  = lane & 15;
  const int sw   = (quad ^ ((l16 >> 1) & 3)) * 8;
  const int r0   = tid >> 2;
  const int kc0  = ((tid & 3) ^ ((r0 >> 1) & 3)) * 8;

  const f16_t* Xg = X + (size_t)(m0 + r0) * 1024 + kc0;
  const f16_t* G1 = W1 + (size_t)(n0 + r0) * 1024 + kc0;
  const f16_t* G2 = W2 + (size_t)(n0 + r0) * 1024 + kc0;

  f32x4 accQ[2][2] = {};
  f32x4 accV[2][2] = {};

  for (int kt = 0; kt < 16; ++kt) {
#pragma unroll
    for (int s = 0; s < 2; ++s) {
      const int ko = s * 32;
      async_copy16(Xg + ko, Xs + s * SZ + tid * 8);
      async_copy16(G1 + ko, W1s + s * SZ + tid * 8);
      async_copy16(G2 + ko, W2s + s * SZ + tid * 8);
    }
    __syncthreads();

#pragma unroll
    for (int s = 0; s < 2; ++s) {
      f16x8 xf[2], w1f[2], w2f[2];
#pragma unroll
      for (int i = 0; i < 2; ++i) {
        xf[i]  = *(const f16x8*)(Xs  + s * SZ + (wr + i * 16 + l16) * 32 + sw);
        w1f[i] = *(const f16x8*)(W1s + s * SZ + (wc + i * 16 + l16) * 32 + sw);
        w2f[i] = *(const f16x8*)(W2s + s * SZ + (wc + i * 16 + l16) * 32 + sw);
      }
#pragma unroll
      for (int i = 0; i < 2; ++i)
#pragma unroll
        for (int j = 0; j < 2; ++j) {
          accQ[i][j] = mfma16(xf[i], w1f[j], accQ[i][j]);
          accV[i][j] = mfma16(xf[i], w2f[j], accV[i][j]);
        }
    }
    __syncthreads();
    Xg += 64; G1 += 64; G2 += 64;
  }

#pragma unroll
  for (int j = 0; j < 2; ++j) {
    const int col = n0 + wc + j * 16 + l16;
    const float bq = b1[col], bv = b2[col];
#pragma unroll
    for (int i = 0; i < 2; ++i)
#pragma unroll
      for (int r = 0; r < 4; ++r) {
        const int row = m0 + wr + i * 16 + quad * 4 + r;
        Q[(size_t)row * 1024 + col] = (f16_t)(accQ[i][j][r] + bq);
        V[(size_t)row * 1024 + col] = (f16_t)(accV[i][j][r] + bv);
      }
  }
}

// ---------------------------------------------------------------------------
// 1b) Vt[b][d][key] = V[b][key][d]. 64x64 tiles through LDS, XOR-swizzled,
//     conflict-free, coalesced both sides. Grid (32 key, 16 d, 4 b).
__global__ __launch_bounds__(256) void vt_kernel(
    const f16_t* __restrict__ V, f16_t* __restrict__ Vt)
{
  __shared__ __align__(16) f16_t Ls[64 * 64];   // 8 KB
  const int key0 = blockIdx.x * 64;
  const int d0   = blockIdx.y * 64;
  const size_t boff = (size_t)blockIdx.z * 2048 * 1024;

  const int tid = threadIdx.x;
#pragma unroll
  for (int rep = 0; rep < 2; ++rep) {
    const int kr = rep * 32 + (tid >> 3);
    const int dc = (tid & 7) * 8;
    f16x8 v = *(const f16x8*)(V + boff + (size_t)(key0 + kr) * 1024 + d0 + dc);
#pragma unroll
    for (int e = 0; e < 8; ++e) {
      const int d = dc + e;
      Ls[d * 64 + (((kr >> 3) ^ (d >> 3)) << 3) + (kr & 7)] = v[e];
    }
  }
  __syncthreads();
#pragma unroll
  for (int rep = 0; rep < 2; ++rep) {
    const int d = rep * 32 + (tid >> 3);
    const int c = tid & 7;
    f16x8 v = *(const f16x8*)(Ls + d * 64 + ((c ^ (d >> 3)) << 3));
    *(f16x8*)(Vt + boff + (size_t)(d0 + d) * 2048 + key0 + c * 8) = v;
  }
}

// ---------------------------------------------------------------------------
// 2) scores: S[b][q][k] = Q[b,q,:] . V[b,k,:], written FP16. 128x128 tile,
//    BK=64, LDS 32 KB, grid 16x16x4 = 1024 (4 blocks/CU), 16 barrier pairs.
__global__ __launch_bounds__(256) void score_kernel(
    const f16_t* __restrict__ Q, const f16_t* __restrict__ V,
    f16_t* __restrict__ S)
{
  __shared__ __align__(16) f16_t As[2 * 128 * 32];   // 16 KB
  __shared__ __align__(16) f16_t Bs[2 * 128 * 32];   // 16 KB
  const int m0 = blockIdx.x * 128;
  const int n0 = blockIdx.y * 128;
  const size_t boff = (size_t)blockIdx.z * 2048 * 1024;

  f32x4 acc[4][4] = {};
  gemm_core<4, 4, 2>(Q + boff + (size_t)m0 * 1024,
                     V + boff + (size_t)n0 * 1024,
                     1024, 1024, 1024 / 64, As, Bs, acc);

  f16_t* Sb = S + (size_t)blockIdx.z * 2048 * 2048;
  const int lane = threadIdx.x & 63;
  const int w    = threadIdx.x >> 6;
  const int wr   = (w >> 1) * 64, wc = (w & 1) * 64;
  const int quad = lane >> 4,     l16 = lane & 15;

#pragma unroll
  for (int i = 0; i < 4; ++i)
#pragma unroll
    for (int j = 0; j < 4; ++j)
#pragma unroll
      for (int r = 0; r < 4; ++r) {
        const int row = m0 + wr + i * 16 + quad * 4 + r;
        const int col = n0 + wc + j * 16 + l16;
        Sb[(size_t)row * 2048 + col] = (f16_t)acc[i][j][r];
      }
}

// ---------------------------------------------------------------------------
// 3) softmax over each 2048-f16 row of S; fp16 P in-place. Each thread owns
//    its 8 elements (reads and writes the same addresses — no cross-thread
//    hazard); exp/max/sum in fp32.
__global__ __launch_bounds__(256) void softmax_kernel(f16_t* __restrict__ S)
{
  f16_t* row = S + (size_t)blockIdx.x * 2048;
  const int tid  = threadIdx.x;
  const int lane = tid & 63;
  const int w    = tid >> 6;

  f16x8 v = *((const f16x8*)row + tid);
  float f[8];
#pragma unroll
  for (int k = 0; k < 8; ++k) f[k] = (float)v[k];

  float m = f[0];
#pragma unroll
  for (int k = 1; k < 8; ++k) m = fmaxf(m, f[k]);
#pragma unroll
  for (int off = 32; off >= 1; off >>= 1) m = fmaxf(m, __shfl_xor(m, off));

  __shared__ float red[4];
  if (lane == 0) red[w] = m;
  __syncthreads();
  m = fmaxf(fmaxf(red[0], red[1]), fmaxf(red[2], red[3]));

  float s = 0.f;
#pragma unroll
  for (int k = 0; k < 8; ++k) { f[k] = __expf(f[k] - m); s += f[k]; }
#pragma unroll
  for (int off = 32; off >= 1; off >>= 1) s += __shfl_xor(s, off);
  __syncthreads();
  if (lane == 0) red[w] = s;
  __syncthreads();
  s = (red[0] + red[1]) + (red[2] + red[3]);
  const float inv = 1.f / s;

  f16x8 o;
#pragma unroll
  for (int k = 0; k < 8; ++k) o[k] = (f16_t)(f[k] * inv);
  *((f16x8*)row + tid) = o;
}

// ---------------------------------------------------------------------------
// 4) out[b][q][d] = sum_k P[b][q][k] * Vt[b][d][k] -> fp32. P pitch 2048 f16.
//    64x128 tile, BK=128 (NS=4, LDS 48 KB, 3 blocks/CU), 16 barrier pairs.
__global__ __launch_bounds__(256) void out_kernel(
    const f16_t* __restrict__ P, const f16_t* __restrict__ Vt,
    float* __restrict__ Out)
{
  __shared__ __align__(16) f16_t As[4 * 64 * 32];    // 16 KB
  __shared__ __align__(16) f16_t Bs[4 * 128 * 32];   // 32 KB
  const int m0 = blockIdx.x * 64;
  const int n0 = blockIdx.y * 128;
  const size_t poff  = (size_t)blockIdx.z * 2048 * 2048;
  const size_t vtoff = (size_t)blockIdx.z * 1024 * 2048;

  f32x4 acc[2][4] = {};
  gemm_core<2, 4, 4>(P + poff + (size_t)m0 * 2048,
                     Vt + vtoff + (size_t)n0 * 2048,
                     2048, 2048, 2048 / 128, As, Bs, acc);

  float* Ob = Out + (size_t)blockIdx.z * 2048 * 1024;
  const int lane = threadIdx.x & 63;
  const int w    = threadIdx.x >> 6;
  const int wr   = (w >> 1) * 32, wc = (w & 1) * 64;
  const int quad = lane >> 4,     l16 = lane & 15;

#pragma unroll
  for (int i = 0; i < 2; ++i)
#pragma unroll
    for (int j = 0; j < 4; ++j)
#pragma unroll
      for (int r = 0; r < 4; ++r) {
        const int row = m0 + wr + i * 16 + quad * 4 + r;
        const int col = n0 + wc + j * 16 + l16;
        Ob[(size_t)row * 1024 + col] = acc[i][j][r];
      }
}

// ---------------------------------------------------------------------------
extern "C" void kernel_launch(void* const* d_in, const int* in_sizes, int n_in,
                              void* d_out, int out_size, void* d_ws, size_t ws_size,
                              hipStream_t stream) {
  const float* x  = (const float*)d_in[0];
  const float* W1 = (const float*)d_in[1];
  const float* b1 = (const float*)d_in[2];
  const float* W2 = (const float*)d_in[3];
  const float* b2 = (const float*)d_in[4];
  float* out = (float*)d_out;

  const size_t QN = (size_t)8192 * 1024;
  const size_t WN = (size_t)1024 * 1024;
  f16_t* xh  = (f16_t*)d_ws;       // 16 MiB
  f16_t* W1h = xh + QN;            //  2 MiB
  f16_t* W2h = W1h + WN;           //  2 MiB
  f16_t* Q   = W2h + WN;           // 16 MiB
  f16_t* V   = Q + QN;             // 16 MiB
  f16_t* Vt  = V + QN;             // 16 MiB [4][1024][2048]
  f16_t* S   = Vt + QN;            // 32 MiB fp16 [4][2048][2048], P in-place

  dim3 blk(256);
  cvt_kernel<<<5120, blk, 0, stream>>>(x, W1, W2, xh, W1h, W2h);
  proj_qv_kernel<<<dim3(128, 16), blk, 0, stream>>>(xh, W1h, W2h, b1, b2, Q, V);
  vt_kernel<<<dim3(32, 16, 4), blk, 0, stream>>>(V, Vt);
  score_kernel<<<dim3(16, 16, 4), blk, 0, stream>>>(Q, V, S);
  softmax_kernel<<<8192, blk, 0, stream>>>(S);
  out_kernel<<<dim3(32, 8, 4), blk, 0, stream>>>(S, Vt, out);
}

// Round 9
// 249.762 us; speedup vs baseline: 1.1672x; 1.0352x over previous
//
#include <hip/hip_runtime.h>
#include <stdint.h>
#include <stddef.h>

// ---------------------------------------------------------------------------
// SelfAttention: out = softmax((x W1^T + b1)(x W2^T + b2)^T) (x W2^T + b2)
// B=4, L=2048, D=1024. fp32 in/out; fp16 MFMA internals.
// Round 9: r8 showed BK-vs-occupancy levers balance at BK=64 / 4 blocks/CU
// (out BK=128 @3/CU lost 57->60). This round: kernel/traffic elimination.
//  - out reverted to BK=64 (r7's measured-best config)
//  - vt_kernel ELIMINATED: proj transposes V in its epilogue through an LDS
//    buffer aliased onto W1s (dead after the K-loop) -> LDS stays 24 KB,
//    saves the 32 MiB V round-trip + one dispatch
//  - score BK=64 + fp16 S + softmax unchanged (measured good)
// XOR k-chunk swizzle everywhere (r3: conflicts 4.2e6 -> 0).
// ---------------------------------------------------------------------------

typedef _Float16  f16_t;
typedef _Float16  f16x8 __attribute__((ext_vector_type(8)));
typedef float     f32x4 __attribute__((ext_vector_type(4)));

__device__ __forceinline__ f32x4 mfma16(f16x8 a, f16x8 b, f32x4 c) {
  return __builtin_amdgcn_mfma_f32_16x16x32_f16(a, b, c, 0, 0, 0);
}

__device__ __forceinline__ void async_copy16(const f16_t* g, f16_t* l) {
  __builtin_amdgcn_global_load_lds(
      (const __attribute__((address_space(1))) unsigned int*)(g),
      (__attribute__((address_space(3))) unsigned int*)(l),
      16, 0, 0);
}

// C = A * B^T on a (RM*32) x (RN*32) tile, K = nk*NS*32, K contiguous.
// 4 waves 2x2; wave quadrant (RM*16) x (RN*16). Per iter: stage NS 32-k
// slices, one barrier pair, NS*RM*RN MFMAs per wave. k-chunks XOR-swizzled.
template <int RM, int RN, int NS>
__device__ __forceinline__ void gemm_core(
    const f16_t* __restrict__ A, const f16_t* __restrict__ B,
    int lda, int ldb, int nk,
    f16_t* __restrict__ As, f16_t* __restrict__ Bs, f32x4 (&acc)[RM][RN])
{
  const int tid  = threadIdx.x;
  const int lane = tid & 63;
  const int w    = tid >> 6;
  const int wr   = (w >> 1) * (RM * 16);
  const int wc   = (w & 1) * (RN * 16);
  const int l16  = lane & 15;
  const int quad = lane >> 4;
  const int sw   = (quad ^ ((l16 >> 1) & 3)) * 8;

  const int r0  = tid >> 2;
  const int kc0 = ((tid & 3) ^ ((r0 >> 1) & 3)) * 8;

  const f16_t* Ag = A + (size_t)r0 * lda + kc0;
  const f16_t* Bg = B + (size_t)r0 * ldb + kc0;

  for (int kt = 0; kt < nk; ++kt) {
#pragma unroll
    for (int s = 0; s < NS; ++s) {
      const int ko = s * 32;
#pragma unroll
      for (int h = 0; h < RM / 2; ++h)
        async_copy16(Ag + ko + (size_t)(64 * h) * lda,
                     As + s * RM * 1024 + (tid + 256 * h) * 8);
#pragma unroll
      for (int h = 0; h < RN / 2; ++h)
        async_copy16(Bg + ko + (size_t)(64 * h) * ldb,
                     Bs + s * RN * 1024 + (tid + 256 * h) * 8);
    }
    __syncthreads();

#pragma unroll
    for (int s = 0; s < NS; ++s) {
      const f16_t* Ac = As + s * RM * 1024;
      const f16_t* Bc = Bs + s * RN * 1024;
      f16x8 af[RM], bf[RN];
#pragma unroll
      for (int i = 0; i < RM; ++i)
        af[i] = *(const f16x8*)(Ac + (wr + i * 16 + l16) * 32 + sw);
#pragma unroll
      for (int j = 0; j < RN; ++j)
        bf[j] = *(const f16x8*)(Bc + (wc + j * 16 + l16) * 32 + sw);
#pragma unroll
      for (int i = 0; i < RM; ++i)
#pragma unroll
        for (int j = 0; j < RN; ++j)
          acc[i][j] = mfma16(af[i], bf[j], acc[i][j]);
    }

    __syncthreads();
    Ag += NS * 32; Bg += NS * 32;
  }
}

// ---------------------------------------------------------------------------
// 0) fp32 -> fp16 for x, W1, W2 in one launch. Grid 5120 x 256 x 8 elems.
__global__ __launch_bounds__(256) void cvt_kernel(
    const float* __restrict__ x, const float* __restrict__ W1,
    const float* __restrict__ W2, f16_t* __restrict__ xh,
    f16_t* __restrict__ W1h, f16_t* __restrict__ W2h)
{
  const size_t XN = (size_t)8192 * 1024;
  const size_t WN = (size_t)1024 * 1024;
  size_t i = ((size_t)blockIdx.x * 256 + threadIdx.x) * 8;
  const float* in; f16_t* out;
  if (i < XN)            { in = x;  out = xh; }
  else if (i < XN + WN)  { in = W1; out = W1h; i -= XN; }
  else                   { in = W2; out = W2h; i -= XN + WN; }
  f32x4 a = *(const f32x4*)(in + i);
  f32x4 b = *(const f32x4*)(in + i + 4);
  f16x8 o;
#pragma unroll
  for (int k = 0; k < 4; ++k) { o[k] = (f16_t)a[k]; o[k + 4] = (f16_t)b[k]; }
  *(f16x8*)(out + i) = o;
}

// ---------------------------------------------------------------------------
// 1) fused projection, 64x64 tiles, BK=64: Q = xW1^T+b1, V = xW2^T+b2, plus
//    Vt[b][d][key] via LDS transpose in the epilogue (buffer aliased onto
//    W1s, which is dead after the K-loop). Grid 128x16=2048.
__global__ __launch_bounds__(256) void proj_qv_kernel(
    const f16_t* __restrict__ X, const f16_t* __restrict__ W1,
    const f16_t* __restrict__ W2, const float* __restrict__ b1,
    const float* __restrict__ b2, f16_t* __restrict__ Q,
    f16_t* __restrict__ V, f16_t* __restrict__ Vt)
{
  __shared__ __align__(16) f16_t Xs[2 * 64 * 32];    // 8 KB
  __shared__ __align__(16) f16_t W1s[2 * 64 * 32];   // 8 KB (reused as Ts)
  __shared__ __align__(16) f16_t W2s[2 * 64 * 32];   // 8 KB
  constexpr int SZ = 64 * 32;

  const int m0 = blockIdx.x * 64;
  const int n0 = blockIdx.y * 64;

  const int tid  = threadIdx.x;
  const int lane = tid & 63;
  const int w    = tid >> 6;
  const int wr   = (w >> 1) * 32;
  const int wc   = (w & 1) * 32;
  const int quad = lane >> 4;
  const int l16  = lane & 15;
  const int sw   = (quad ^ ((l16 >> 1) & 3)) * 8;
  const int r0   = tid >> 2;
  const int kc0  = ((tid & 3) ^ ((r0 >> 1) & 3)) * 8;

  const f16_t* Xg = X + (size_t)(m0 + r0) * 1024 + kc0;
  const f16_t* G1 = W1 + (size_t)(n0 + r0) * 1024 + kc0;
  const f16_t* G2 = W2 + (size_t)(n0 + r0) * 1024 + kc0;

  f32x4 accQ[2][2] = {};
  f32x4 accV[2][2] = {};

  for (int kt = 0; kt < 16; ++kt) {
#pragma unroll
    for (int s = 0; s < 2; ++s) {
      const int ko = s * 32;
      async_copy16(Xg + ko, Xs + s * SZ + tid * 8);
      async_copy16(G1 + ko, W1s + s * SZ + tid * 8);
      async_copy16(G2 + ko, W2s + s * SZ + tid * 8);
    }
    __syncthreads();

#pragma unroll
    for (int s = 0; s < 2; ++s) {
      f16x8 xf[2], w1f[2], w2f[2];
#pragma unroll
      for (int i = 0; i < 2; ++i) {
        xf[i]  = *(const f16x8*)(Xs  + s * SZ + (wr + i * 16 + l16) * 32 + sw);
        w1f[i] = *(const f16x8*)(W1s + s * SZ + (wc + i * 16 + l16) * 32 + sw);
        w2f[i] = *(const f16x8*)(W2s + s * SZ + (wc + i * 16 + l16) * 32 + sw);
      }
#pragma unroll
      for (int i = 0; i < 2; ++i)
#pragma unroll
        for (int j = 0; j < 2; ++j) {
          accQ[i][j] = mfma16(xf[i], w1f[j], accQ[i][j]);
          accV[i][j] = mfma16(xf[i], w2f[j], accV[i][j]);
        }
    }
    __syncthreads();
    Xg += 64; G1 += 64; G2 += 64;
  }

  // epilogue: Q/V natural stores; V also into Ts (aliased onto W1s) for the
  // transposed write. Chunk placement XOR-swizzled by (col>>3) so the
  // vector reads below are conflict-free (same layout as old vt_kernel).
  f16_t* Ts = W1s;   // 64x64 f16 = 8 KB, fits exactly; W1s dead post-loop
#pragma unroll
  for (int j = 0; j < 2; ++j) {
    const int c   = wc + j * 16 + l16;        // local col (d)
    const int col = n0 + c;
    const float bq = b1[col], bv = b2[col];
#pragma unroll
    for (int i = 0; i < 2; ++i)
#pragma unroll
      for (int r = 0; r < 4; ++r) {
        const int k   = wr + i * 16 + quad * 4 + r;   // local row (key)
        const int row = m0 + k;
        const float q = accQ[i][j][r] + bq;
        const float v = accV[i][j][r] + bv;
        Q[(size_t)row * 1024 + col] = (f16_t)q;
        V[(size_t)row * 1024 + col] = (f16_t)v;
        Ts[c * 64 + (((k >> 3) ^ (c >> 3)) << 3) + (k & 7)] = (f16_t)v;
      }
  }
  __syncthreads();

  // coalesced Vt stores: Vt[b][n0+d][key0 .. key0+63]
  const size_t vtbase = ((size_t)(m0 >> 11) << 21) + (size_t)n0 * 2048 + (m0 & 2047);
#pragma unroll
  for (int rep = 0; rep < 2; ++rep) {
    const int d = rep * 32 + (tid >> 3);   // local col 0..63
    const int c = tid & 7;                 // key chunk 0..7
    f16x8 vv = *(const f16x8*)(Ts + d * 64 + ((c ^ (d >> 3)) << 3));
    *(f16x8*)(Vt + vtbase + (size_t)d * 2048 + c * 8) = vv;
  }
}

// ---------------------------------------------------------------------------
// 2) scores: S[b][q][k] = Q[b,q,:] . V[b,k,:], written FP16. 128x128 tile,
//    BK=64, LDS 32 KB, grid 16x16x4 = 1024 (4 blocks/CU), 16 barrier pairs.
__global__ __launch_bounds__(256) void score_kernel(
    const f16_t* __restrict__ Q, const f16_t* __restrict__ V,
    f16_t* __restrict__ S)
{
  __shared__ __align__(16) f16_t As[2 * 128 * 32];   // 16 KB
  __shared__ __align__(16) f16_t Bs[2 * 128 * 32];   // 16 KB
  const int m0 = blockIdx.x * 128;
  const int n0 = blockIdx.y * 128;
  const size_t boff = (size_t)blockIdx.z * 2048 * 1024;

  f32x4 acc[4][4] = {};
  gemm_core<4, 4, 2>(Q + boff + (size_t)m0 * 1024,
                     V + boff + (size_t)n0 * 1024,
                     1024, 1024, 1024 / 64, As, Bs, acc);

  f16_t* Sb = S + (size_t)blockIdx.z * 2048 * 2048;
  const int lane = threadIdx.x & 63;
  const int w    = threadIdx.x >> 6;
  const int wr   = (w >> 1) * 64, wc = (w & 1) * 64;
  const int quad = lane >> 4,     l16 = lane & 15;

#pragma unroll
  for (int i = 0; i < 4; ++i)
#pragma unroll
    for (int j = 0; j < 4; ++j)
#pragma unroll
      for (int r = 0; r < 4; ++r) {
        const int row = m0 + wr + i * 16 + quad * 4 + r;
        const int col = n0 + wc + j * 16 + l16;
        Sb[(size_t)row * 2048 + col] = (f16_t)acc[i][j][r];
      }
}

// ---------------------------------------------------------------------------
// 3) softmax over each 2048-f16 row of S; fp16 P in-place. Each thread owns
//    its 8 elements; exp/max/sum in fp32.
__global__ __launch_bounds__(256) void softmax_kernel(f16_t* __restrict__ S)
{
  f16_t* row = S + (size_t)blockIdx.x * 2048;
  const int tid  = threadIdx.x;
  const int lane = tid & 63;
  const int w    = tid >> 6;

  f16x8 v = *((const f16x8*)row + tid);
  float f[8];
#pragma unroll
  for (int k = 0; k < 8; ++k) f[k] = (float)v[k];

  float m = f[0];
#pragma unroll
  for (int k = 1; k < 8; ++k) m = fmaxf(m, f[k]);
#pragma unroll
  for (int off = 32; off >= 1; off >>= 1) m = fmaxf(m, __shfl_xor(m, off));

  __shared__ float red[4];
  if (lane == 0) red[w] = m;
  __syncthreads();
  m = fmaxf(fmaxf(red[0], red[1]), fmaxf(red[2], red[3]));

  float s = 0.f;
#pragma unroll
  for (int k = 0; k < 8; ++k) { f[k] = __expf(f[k] - m); s += f[k]; }
#pragma unroll
  for (int off = 32; off >= 1; off >>= 1) s += __shfl_xor(s, off);
  __syncthreads();
  if (lane == 0) red[w] = s;
  __syncthreads();
  s = (red[0] + red[1]) + (red[2] + red[3]);
  const float inv = 1.f / s;

  f16x8 o;
#pragma unroll
  for (int k = 0; k < 8; ++k) o[k] = (f16_t)(f[k] * inv);
  *((f16x8*)row + tid) = o;
}

// ---------------------------------------------------------------------------
// 4) out[b][q][d] = sum_k P[b][q][k] * Vt[b][d][k] -> fp32. P pitch 2048 f16.
//    64x128 tile, BK=64 (r7's measured-best: LDS 24 KB, 4 blocks/CU).
__global__ __launch_bounds__(256) void out_kernel(
    const f16_t* __restrict__ P, const f16_t* __restrict__ Vt,
    float* __restrict__ Out)
{
  __shared__ __align__(16) f16_t As[2 * 64 * 32];    // 8 KB
  __shared__ __align__(16) f16_t Bs[2 * 128 * 32];   // 16 KB
  const int m0 = blockIdx.x * 64;
  const int n0 = blockIdx.y * 128;
  const size_t poff  = (size_t)blockIdx.z * 2048 * 2048;
  const size_t vtoff = (size_t)blockIdx.z * 1024 * 2048;

  f32x4 acc[2][4] = {};
  gemm_core<2, 4, 2>(P + poff + (size_t)m0 * 2048,
                     Vt + vtoff + (size_t)n0 * 2048,
                     2048, 2048, 2048 / 64, As, Bs, acc);

  float* Ob = Out + (size_t)blockIdx.z * 2048 * 1024;
  const int lane = threadIdx.x & 63;
  const int w    = threadIdx.x >> 6;
  const int wr   = (w >> 1) * 32, wc = (w & 1) * 64;
  const int quad = lane >> 4,     l16 = lane & 15;

#pragma unroll
  for (int i = 0; i < 2; ++i)
#pragma unroll
    for (int j = 0; j < 4; ++j)
#pragma unroll
      for (int r = 0; r < 4; ++r) {
        const int row = m0 + wr + i * 16 + quad * 4 + r;
        const int col = n0 + wc + j * 16 + l16;
        Ob[(size_t)row * 1024 + col] = acc[i][j][r];
      }
}

// ---------------------------------------------------------------------------
extern "C" void kernel_launch(void* const* d_in, const int* in_sizes, int n_in,
                              void* d_out, int out_size, void* d_ws, size_t ws_size,
                              hipStream_t stream) {
  const float* x  = (const float*)d_in[0];
  const float* W1 = (const float*)d_in[1];
  const float* b1 = (const float*)d_in[2];
  const float* W2 = (const float*)d_in[3];
  const float* b2 = (const float*)d_in[4];
  float* out = (float*)d_out;

  const size_t QN = (size_t)8192 * 1024;
  const size_t WN = (size_t)1024 * 1024;
  f16_t* xh  = (f16_t*)d_ws;       // 16 MiB
  f16_t* W1h = xh + QN;            //  2 MiB
  f16_t* W2h = W1h + WN;           //  2 MiB
  f16_t* Q   = W2h + WN;           // 16 MiB
  f16_t* V   = Q + QN;             // 16 MiB
  f16_t* Vt  = V + QN;             // 16 MiB [4][1024][2048]
  f16_t* S   = Vt + QN;            // 32 MiB fp16 [4][2048][2048], P in-place

  dim3 blk(256);
  cvt_kernel<<<5120, blk, 0, stream>>>(x, W1, W2, xh, W1h, W2h);
  proj_qv_kernel<<<dim3(128, 16), blk, 0, stream>>>(xh, W1h, W2h, b1, b2, Q, V, Vt);
  score_kernel<<<dim3(16, 16, 4), blk, 0, stream>>>(Q, V, S);
  softmax_kernel<<<8192, blk, 0, stream>>>(S);
  out_kernel<<<dim3(32, 8, 4), blk, 0, stream>>>(S, Vt, out);
}